// Round 7
// baseline (360.346 us; speedup 1.0000x reference)
//
#include <hip/hip_runtime.h>

// MHA fused: B=2, S=2048, D=1024, H=16, DK=64.
// Round 7:
//  - GEMMs rebuilt around the round-6 finding that the LDS pipe (72 KB/block-
//    kstep, 8-way-conflicted frag reads) was the ~500 TF ceiling:
//      * A-operand fragments load DIRECTLY global->regs (A rows have zero
//        cross-wave reuse; frag layout row=lo16,k=quad*8 is native row-major),
//        register-prefetched one kstep ahead. A never touches LDS.
//      * W tile (real 4-wave reuse) stays in LDS, double-buffered, with XOR
//        chunk swizzle p = c ^ ((r>>1)&3): global_load_lds DMA layout stays
//        legal (only global source offset permuted), frag reads 2-way = free.
//    LDS traffic 72 -> 40 KB/block-kstep, conflicts ~0 -> MFMA-bound.
//  - Attention unchanged (round-6 showed it is not MFMA-bound; next target).

constexpr int BB = 2;
constexpr int SS = 2048;
constexpr int DD = 1024;
constexpr int HH = 16;
constexpr int DKK = 64;

typedef float f32x4 __attribute__((ext_vector_type(4)));
typedef __bf16 bf16x8 __attribute__((ext_vector_type(8)));
typedef short s16x8 __attribute__((ext_vector_type(8)));
typedef short s16x4 __attribute__((ext_vector_type(4)));

#define DEV static __device__ __forceinline__

DEV f32x4 mfma16(s16x8 a, s16x8 b, f32x4 c) {
  return __builtin_amdgcn_mfma_f32_16x16x32_bf16(
      __builtin_bit_cast(bf16x8, a), __builtin_bit_cast(bf16x8, b), c, 0, 0, 0);
}

DEV void split1(float x, short& h, short& l) {  // x ~= hi + lo (both bf16)
  unsigned u = __float_as_uint(x);
  h = (short)(u >> 16);
  float hf = __uint_as_float(u & 0xffff0000u);
  l = (short)(__float_as_uint(x - hf) >> 16);
}
DEV short f2bf_rne(float x) {  // round-to-nearest-even bf16
  unsigned u = __float_as_uint(x);
  return (short)((u + 0x7fffu + ((u >> 16) & 1u)) >> 16);
}
DEV s16x8 load8s(const short* p) { return *(const s16x8*)p; }

DEV void gld_lds16(const short* g, short* l) {
  __builtin_amdgcn_global_load_lds(
      (const __attribute__((address_space(1))) void*)g,
      (__attribute__((address_space(3))) void*)l, 16, 0, 0);
}

// ---------------------------------------------------------------- elementwise
__global__ __launch_bounds__(256) void split_pair(const float* __restrict__ X,
                                                  short* __restrict__ H,
                                                  short* __restrict__ L) {
  int i = (blockIdx.x * 256 + threadIdx.x) * 4;
  float4 x = *(const float4*)(X + i);
  float xs[4] = {x.x, x.y, x.z, x.w};
  s16x4 h4, l4;
#pragma unroll
  for (int e = 0; e < 4; ++e) {
    short h, l;
    split1(xs[e], h, l);
    h4[e] = h;
    l4[e] = l;
  }
  *(s16x4*)(H + i) = h4;
  *(s16x4*)(L + i) = l4;
}

__global__ __launch_bounds__(256) void cast_rne(const float* __restrict__ X,
                                                short* __restrict__ Y) {
  int i = (blockIdx.x * 256 + threadIdx.x) * 4;
  float4 x = *(const float4*)(X + i);
  float xs[4] = {x.x, x.y, x.z, x.w};
  s16x4 y4;
#pragma unroll
  for (int e = 0; e < 4; ++e) y4[e] = f2bf_rne(xs[e]);
  *(s16x4*)(Y + i) = y4;
}

// ---------------------------------------------------------------- merged Q+K projection
// Grid 1024: blocks 0-511 -> Q (plain bf16 out), 512-1023 -> K (hi/lo out).
// Tile 128(M) x 64(N), BK=32. A frags global->regs (prefetched); W in LDS
// (dbuf, XOR-swizzled).
__global__ __launch_bounds__(256) void gemm_qk(
    const short* __restrict__ qAh, const short* __restrict__ qAl,
    const short* __restrict__ Wqh, const short* __restrict__ Wql,
    const float* __restrict__ bq, short* __restrict__ Qo,
    const short* __restrict__ kAh, const short* __restrict__ kAl,
    const short* __restrict__ Wkh, const short* __restrict__ Wkl,
    const float* __restrict__ bk, short* __restrict__ Kho,
    short* __restrict__ Klo) {
  __shared__ short lds[2][4096];  // per buf: Wh[2048] Wl[2048]

  const int tid = threadIdx.x;
  const int lane = tid & 63, wv = tid >> 6;
  const int lo16 = lane & 15, quad = lane >> 4;
  const int sel = blockIdx.x >> 9;  // 0 = Q, 1 = K
  const int bid = blockIdx.x & 511;
  const int m0 = (bid & 31) * 128;
  const int n0 = (bid >> 5) * 64;

  const short* Agh = sel ? kAh : qAh;
  const short* Agl = sel ? kAl : qAl;
  const short* Wgh = sel ? Wkh : Wqh;
  const short* Wgl = sel ? Wkl : Wql;
  const float* bias = sel ? bk : bq;

  f32x4 acc[2][4];
#pragma unroll
  for (int mt = 0; mt < 2; ++mt)
#pragma unroll
    for (int nt = 0; nt < 4; ++nt) acc[mt][nt] = f32x4{0.f, 0.f, 0.f, 0.f};

  // W staging: thread covers physical (row wr, chunk wp); source chunk XOR'd.
  const int wr = tid >> 2, wp = tid & 3;
  const size_t wsrc = (size_t)(n0 + wr) * DD + (wp ^ ((wr >> 1) & 3)) * 8;
  // W fragment read: physical chunk for logical chunk `quad` at row lo16+16nt.
  const int pq = quad ^ ((lo16 >> 1) & 3);

  // A fragment addresses (this wave's rows, native layout).
  const size_t a0 = (size_t)(m0 + wv * 32 + lo16) * DD + quad * 8;
  const size_t a1 = a0 + (size_t)16 * DD;

  s16x8 ah[2], al[2];
  ah[0] = load8s(Agh + a0);
  ah[1] = load8s(Agh + a1);
  al[0] = load8s(Agl + a0);
  al[1] = load8s(Agl + a1);
  gld_lds16(Wgh + wsrc, &lds[0][tid * 8]);
  gld_lds16(Wgl + wsrc, &lds[0][2048 + tid * 8]);

  for (int kk = 0; kk < DD / 32; ++kk) {
    __syncthreads();
    s16x8 ahn[2], aln[2];
    const bool more = (kk + 1 < DD / 32);
    if (more) {
      const int k1 = (kk + 1) * 32;
      gld_lds16(Wgh + wsrc + k1, &lds[(kk + 1) & 1][tid * 8]);
      gld_lds16(Wgl + wsrc + k1, &lds[(kk + 1) & 1][2048 + tid * 8]);
      ahn[0] = load8s(Agh + a0 + k1);
      ahn[1] = load8s(Agh + a1 + k1);
      aln[0] = load8s(Agl + a0 + k1);
      aln[1] = load8s(Agl + a1 + k1);
    }
    const short* sWh = lds[kk & 1];
    const short* sWl = lds[kk & 1] + 2048;
    s16x8 wh[4], wl[4];
#pragma unroll
    for (int nt = 0; nt < 4; ++nt) {
      wh[nt] = *(const s16x8*)&sWh[(nt * 16 + lo16) * 32 + pq * 8];
      wl[nt] = *(const s16x8*)&sWl[(nt * 16 + lo16) * 32 + pq * 8];
    }
#pragma unroll
    for (int mt = 0; mt < 2; ++mt)
#pragma unroll
      for (int nt = 0; nt < 4; ++nt) {
        acc[mt][nt] = mfma16(ah[mt], wh[nt], acc[mt][nt]);
        acc[mt][nt] = mfma16(ah[mt], wl[nt], acc[mt][nt]);
        acc[mt][nt] = mfma16(al[mt], wh[nt], acc[mt][nt]);
      }
    if (more) {
      ah[0] = ahn[0];
      ah[1] = ahn[1];
      al[0] = aln[0];
      al[1] = aln[1];
    }
  }

#pragma unroll
  for (int mt = 0; mt < 2; ++mt)
#pragma unroll
    for (int nt = 0; nt < 4; ++nt) {
      const int n = n0 + nt * 16 + lo16;
      const float bv = bias[n];
#pragma unroll
      for (int r = 0; r < 4; ++r) {
        const int m = m0 + wv * 32 + mt * 16 + quad * 4 + r;
        const float val = acc[mt][nt][r] + bv;
        const int b = m >> 11, s = m & 2047;
        const int h = n >> 6, dk = n & 63;
        size_t idx = ((size_t)(b * HH + h) * SS + s) * DKK + dk;
        if (sel == 0) {
          Qo[idx] = f2bf_rne(val);
        } else {
          short hh, ll;
          split1(val, hh, ll);
          Kho[idx] = hh;
          Klo[idx] = ll;
        }
      }
    }
}

// ---------------------------------------------------------------- GEMM C = A @ W^T + b
// A frags global->regs (prefetched); W in LDS (dbuf, XOR-swizzled).
// EPI 1: plain A/W, out bf16 -> [B,H,DK,S] (V transposed)
// EPI 2: split A/W, out fp32 -> [4096,1024] (final output)
template <int SPLIT, int EPI>
__global__ __launch_bounds__(256) void gemm_tile(
    const short* __restrict__ Agh, const short* __restrict__ Agl,
    const short* __restrict__ Wgh, const short* __restrict__ Wgl,
    const float* __restrict__ bias, void* __restrict__ O1, void* __restrict__ O2) {
  __shared__ short lds[2][4096];

  const int tid = threadIdx.x;
  const int lane = tid & 63, wv = tid >> 6;
  const int lo16 = lane & 15, quad = lane >> 4;
  const int m0 = (blockIdx.x & 31) * 128;
  const int n0 = (blockIdx.x >> 5) * 64;

  f32x4 acc[2][4];
#pragma unroll
  for (int mt = 0; mt < 2; ++mt)
#pragma unroll
    for (int nt = 0; nt < 4; ++nt) acc[mt][nt] = f32x4{0.f, 0.f, 0.f, 0.f};

  const int wr = tid >> 2, wp = tid & 3;
  const size_t wsrc = (size_t)(n0 + wr) * DD + (wp ^ ((wr >> 1) & 3)) * 8;
  const int pq = quad ^ ((lo16 >> 1) & 3);

  const size_t a0 = (size_t)(m0 + wv * 32 + lo16) * DD + quad * 8;
  const size_t a1 = a0 + (size_t)16 * DD;

  s16x8 ah[2], al[2];
  ah[0] = load8s(Agh + a0);
  ah[1] = load8s(Agh + a1);
  if constexpr (SPLIT) {
    al[0] = load8s(Agl + a0);
    al[1] = load8s(Agl + a1);
  }
  gld_lds16(Wgh + wsrc, &lds[0][tid * 8]);
  if constexpr (SPLIT) gld_lds16(Wgl + wsrc, &lds[0][2048 + tid * 8]);

  for (int kk = 0; kk < DD / 32; ++kk) {
    __syncthreads();
    s16x8 ahn[2], aln[2];
    const bool more = (kk + 1 < DD / 32);
    if (more) {
      const int k1 = (kk + 1) * 32;
      gld_lds16(Wgh + wsrc + k1, &lds[(kk + 1) & 1][tid * 8]);
      if constexpr (SPLIT)
        gld_lds16(Wgl + wsrc + k1, &lds[(kk + 1) & 1][2048 + tid * 8]);
      ahn[0] = load8s(Agh + a0 + k1);
      ahn[1] = load8s(Agh + a1 + k1);
      if constexpr (SPLIT) {
        aln[0] = load8s(Agl + a0 + k1);
        aln[1] = load8s(Agl + a1 + k1);
      }
    }
    const short* sWh = lds[kk & 1];
    const short* sWl = lds[kk & 1] + 2048;
    s16x8 wh[4], wl[4];
#pragma unroll
    for (int nt = 0; nt < 4; ++nt) {
      wh[nt] = *(const s16x8*)&sWh[(nt * 16 + lo16) * 32 + pq * 8];
      if constexpr (SPLIT)
        wl[nt] = *(const s16x8*)&sWl[(nt * 16 + lo16) * 32 + pq * 8];
    }
#pragma unroll
    for (int mt = 0; mt < 2; ++mt)
#pragma unroll
      for (int nt = 0; nt < 4; ++nt) {
        acc[mt][nt] = mfma16(ah[mt], wh[nt], acc[mt][nt]);
        if constexpr (SPLIT) {
          acc[mt][nt] = mfma16(ah[mt], wl[nt], acc[mt][nt]);
          acc[mt][nt] = mfma16(al[mt], wh[nt], acc[mt][nt]);
        }
      }
    if (more) {
      ah[0] = ahn[0];
      ah[1] = ahn[1];
      if constexpr (SPLIT) {
        al[0] = aln[0];
        al[1] = aln[1];
      }
    }
  }

#pragma unroll
  for (int mt = 0; mt < 2; ++mt)
#pragma unroll
    for (int nt = 0; nt < 4; ++nt) {
      const int n = n0 + nt * 16 + lo16;
      const float bv = bias[n];
#pragma unroll
      for (int r = 0; r < 4; ++r) {
        const int m = m0 + wv * 32 + mt * 16 + quad * 4 + r;
        const float val = acc[mt][nt][r] + bv;
        const int b = m >> 11, s = m & 2047;
        const int h = n >> 6, dk = n & 63;
        if constexpr (EPI == 1) {
          size_t idx = ((size_t)(b * HH + h) * DKK + dk) * SS + s;
          ((short*)O1)[idx] = f2bf_rne(val);
        } else {
          ((float*)O1)[(size_t)m * DD + n] = val;
        }
      }
    }
}

// ---------------------------------------------------------------- flash attention
// Block = 128 q-rows of one head (4 waves x 32 rows). K/V staged in LDS per
// 64-key iteration; next tile register-prefetched. No-max softmax. Q plain
// bf16; K hi/lo (2-term QK MFMA).
constexpr int PAD = 68;
constexpr int NKB = SS / 64;  // 32

__global__ __launch_bounds__(256, 2) void mha_attn(
    const short* __restrict__ Qh, const short* __restrict__ Kh,
    const short* __restrict__ Kl, const short* __restrict__ Vt,
    const int* __restrict__ mask, short* __restrict__ Ah,
    short* __restrict__ Al) {
  __shared__ short sKh[64 * PAD];
  __shared__ short sKl[64 * PAD];
  __shared__ short sV[64 * PAD];
  __shared__ short sP[4][32 * PAD];

  const int tid = threadIdx.x;
  const int lane = tid & 63, wv = tid >> 6;
  const int lo16 = lane & 15, quad = lane >> 4;
  const int bid = blockIdx.x;  // 512 blocks
  const int head = (bid & 7) * 4 + ((bid >> 3) & 3);  // = b*16 + h
  const int qblk = bid >> 5;                          // 0..15
  const int q0 = qblk * 128 + wv * 32;                // this wave's 32 q rows
  const int b = head >> 4;

  const size_t hbase = (size_t)head * SS;

  s16x8 qh[2][2];
#pragma unroll
  for (int rt = 0; rt < 2; ++rt) {
    size_t qb = (hbase + q0 + rt * 16 + lo16) * DKK + quad * 8;
#pragma unroll
    for (int c = 0; c < 2; ++c) qh[rt][c] = load8s(Qh + qb + c * 32);
  }

  f32x4 Oacc[2][4];
#pragma unroll
  for (int rt = 0; rt < 2; ++rt)
#pragma unroll
    for (int t = 0; t < 4; ++t) Oacc[rt][t] = f32x4{0.f, 0.f, 0.f, 0.f};
  float lsum[2][4];
#pragma unroll
  for (int rt = 0; rt < 2; ++rt)
#pragma unroll
    for (int r = 0; r < 4; ++r) lsum[rt][r] = 0.f;

  const int srow = tid >> 2;
  const int scol0 = (tid & 3) * 8;

  s16x8 rKh[2], rKl[2], rV[2];
#pragma unroll
  for (int i = 0; i < 2; ++i) {
    const int sc_ = scol0 + i * 32;
    rKh[i] = load8s(Kh + (hbase + srow) * DKK + sc_);
    rKl[i] = load8s(Kl + (hbase + srow) * DKK + sc_);
    rV[i] = load8s(Vt + ((size_t)head * DKK + srow) * SS + sc_);
  }

  for (int kb = 0; kb < NKB; ++kb) {
    const int k0g = kb * 64;
#pragma unroll
    for (int i = 0; i < 2; ++i) {
      const int sc_ = scol0 + i * 32;
      *(s16x8*)&sKh[srow * PAD + sc_] = rKh[i];
      *(s16x8*)&sKl[srow * PAD + sc_] = rKl[i];
      *(s16x8*)&sV[srow * PAD + sc_] = rV[i];
    }
    __syncthreads();

    if (kb + 1 < NKB) {
      const int k0n = k0g + 64;
#pragma unroll
      for (int i = 0; i < 2; ++i) {
        const int sc_ = scol0 + i * 32;
        rKh[i] = load8s(Kh + (hbase + k0n + srow) * DKK + sc_);
        rKl[i] = load8s(Kl + (hbase + k0n + srow) * DKK + sc_);
        rV[i] = load8s(Vt + ((size_t)head * DKK + srow) * SS + k0n + sc_);
      }
    }

    f32x4 sc4[2][4];
    int mv[4];
#pragma unroll
    for (int sub = 0; sub < 4; ++sub) {
      mv[sub] = mask[b * SS + k0g + sub * 16 + lo16];
      sc4[0][sub] = f32x4{0.f, 0.f, 0.f, 0.f};
      sc4[1][sub] = f32x4{0.f, 0.f, 0.f, 0.f};
      const int krow = sub * 16 + lo16;
#pragma unroll
      for (int c = 0; c < 2; ++c) {
        s16x8 kh = *(const s16x8*)&sKh[krow * PAD + c * 32 + quad * 8];
        s16x8 kl = *(const s16x8*)&sKl[krow * PAD + c * 32 + quad * 8];
#pragma unroll
        for (int rt = 0; rt < 2; ++rt) {
          sc4[rt][sub] = mfma16(qh[rt][c], kh, sc4[rt][sub]);
          sc4[rt][sub] = mfma16(qh[rt][c], kl, sc4[rt][sub]);
        }
      }
    }

#pragma unroll
    for (int rt = 0; rt < 2; ++rt)
#pragma unroll
      for (int sub = 0; sub < 4; ++sub)
#pragma unroll
        for (int r = 0; r < 4; ++r) {
          float p = __expf(sc4[rt][sub][r] * 0.125f);
          p = mv[sub] ? p : 0.f;
          lsum[rt][r] += p;
          sP[wv][(rt * 16 + quad * 4 + r) * PAD + sub * 16 + lo16] = f2bf_rne(p);
        }

    s16x8 pa[2][2];
#pragma unroll
    for (int rt = 0; rt < 2; ++rt)
#pragma unroll
      for (int c = 0; c < 2; ++c)
        pa[rt][c] = *(const s16x8*)&sP[wv][(rt * 16 + lo16) * PAD + c * 32 + quad * 8];
#pragma unroll
    for (int t = 0; t < 4; ++t)
#pragma unroll
      for (int c = 0; c < 2; ++c) {
        s16x8 vb = *(const s16x8*)&sV[(t * 16 + lo16) * PAD + c * 32 + quad * 8];
#pragma unroll
        for (int rt = 0; rt < 2; ++rt)
          Oacc[rt][t] = mfma16(pa[rt][c], vb, Oacc[rt][t]);
      }
    __syncthreads();
  }

  const int h = head & 15;
#pragma unroll
  for (int rt = 0; rt < 2; ++rt)
#pragma unroll
    for (int r = 0; r < 4; ++r) {
      float s = lsum[rt][r];
#pragma unroll
      for (int off = 1; off < 16; off <<= 1) s += __shfl_xor(s, off);
      const float rinv = 1.0f / s;
#pragma unroll
      for (int t = 0; t < 4; ++t) {
        const float val = Oacc[rt][t][r] * rinv;
        const int row = q0 + rt * 16 + quad * 4 + r;
        const int col = h * DKK + t * 16 + lo16;
        const size_t idx = ((size_t)b * SS + row) * DD + col;
        short hh, ll;
        split1(val, hh, ll);
        Ah[idx] = hh;
        Al[idx] = ll;
      }
    }
}

// ---------------------------------------------------------------- launch
extern "C" void kernel_launch(void* const* d_in, const int* in_sizes, int n_in,
                              void* d_out, int out_size, void* d_ws, size_t ws_size,
                              hipStream_t stream) {
  const float* q = (const float*)d_in[0];
  const float* k = (const float*)d_in[1];
  const float* v = (const float*)d_in[2];
  const int* mask = (const int*)d_in[3];
  const float* Wq = (const float*)d_in[4];
  const float* bq = (const float*)d_in[5];
  const float* Wk = (const float*)d_in[6];
  const float* bk = (const float*)d_in[7];
  const float* Wv = (const float*)d_in[8];
  const float* bv = (const float*)d_in[9];
  const float* Wo = (const float*)d_in[10];
  const float* bo = (const float*)d_in[11];

  char* ws = (char*)d_ws;
  size_t off = 0;
  auto take = [&](size_t bytes) {
    char* p = ws + off;
    off += (bytes + 255) & ~(size_t)255;
    return p;
  };
  const size_t WE = (size_t)DD * DD;       // 1,048,576
  const size_t TE = (size_t)BB * SS * DD;  // 4,194,304

  short* Wqh = (short*)take(WE * 2);
  short* Wql = (short*)take(WE * 2);
  short* Wkh = (short*)take(WE * 2);
  short* Wkl = (short*)take(WE * 2);
  short* Wvh = (short*)take(WE * 2);
  short* Woh = (short*)take(WE * 2);
  short* Wol = (short*)take(WE * 2);
  short* qH = (short*)take(TE * 2);
  short* qL = (short*)take(TE * 2);
  short* kH = (short*)take(TE * 2);
  short* kL = (short*)take(TE * 2);
  short* Qh = (short*)take(TE * 2);
  short* Kh = (short*)take(TE * 2);
  short* Kl = (short*)take(TE * 2);
  (void)ws_size;  // 70 MB peak (aliased below)
  // aliases (lifetimes disjoint on the serial stream):
  short* vH = qH;  // v cast, after gemm_qk consumed qH
  short* Vt = qL;  // V-proj out, after gemm_qk consumed qL
  short* aH = kH;  // attn out hi, after gemm_qk consumed kH
  short* aL = kL;  // attn out lo

  // weights
  split_pair<<<1024, 256, 0, stream>>>(Wq, Wqh, Wql);
  split_pair<<<1024, 256, 0, stream>>>(Wk, Wkh, Wkl);
  split_pair<<<1024, 256, 0, stream>>>(Wo, Woh, Wol);
  cast_rne<<<1024, 256, 0, stream>>>(Wv, Wvh);

  // activation splits
  split_pair<<<4096, 256, 0, stream>>>(q, qH, qL);
  split_pair<<<4096, 256, 0, stream>>>(k, kH, kL);

  // merged Q+K projection
  gemm_qk<<<1024, 256, 0, stream>>>(qH, qL, Wqh, Wql, bq, Qh,
                                    kH, kL, Wkh, Wkl, bk, Kh, Kl);

  // V projection (plain bf16, transposed output)
  cast_rne<<<4096, 256, 0, stream>>>(v, vH);
  gemm_tile<0, 1><<<512, 256, 0, stream>>>(vH, nullptr, Wvh, nullptr, bv, Vt, nullptr);

  // attention
  mha_attn<<<512, 256, 0, stream>>>(Qh, Kh, Kl, Vt, mask, aH, aL);

  // output projection
  gemm_tile<1, 2><<<512, 256, 0, stream>>>(aH, aL, Woh, Wol, bo, d_out, nullptr);
}